// Round 1
// baseline (750.521 us; speedup 1.0000x reference)
//
#include <hip/hip_runtime.h>
#include <hip/hip_bf16.h>
#include <math.h>

#define BB 8
#define FF 16
#define DD 256
#define HH 64
#define WW 64
#define OT 8    // output channels per conv block
#define TS 32   // spatial tile (32x32)

// ---------------------------------------------------------------------------
// Kernel 1: build per-sample demodulated filters.
// grid = (o=256, b=8), block = 256 (thread = input channel i).
// kflt layout: [b][o][i][9] fp32
// ---------------------------------------------------------------------------
__global__ __launch_bounds__(256) void prep_filter(
    const float* __restrict__ bank_request,   // (B, F)
    const float* __restrict__ style,          // (B, 1, D, 1, 1)
    const float* __restrict__ bank_weight,    // (F, D, D, 3, 3)
    float* __restrict__ kflt)                 // (B, D, D, 9)
{
    const int o = blockIdx.x;
    const int b = blockIdx.y;
    const int i = threadIdx.x;   // 0..255

    // softmax over bank_request[b][:] (uniform across block -> scalar loads)
    float wreq[FF];
    float m = -1e30f;
#pragma unroll
    for (int f = 0; f < FF; ++f) {
        wreq[f] = bank_request[b * FF + f];
        m = fmaxf(m, wreq[f]);
    }
    float s = 0.f;
#pragma unroll
    for (int f = 0; f < FF; ++f) {
        wreq[f] = __expf(wreq[f] - m);
        s += wreq[f];
    }
    const float inv = 1.0f / s;

    float v[9];
#pragma unroll
    for (int j = 0; j < 9; ++j) v[j] = 0.f;

#pragma unroll
    for (int f = 0; f < FF; ++f) {
        const float wf = wreq[f] * inv;
        const float* bw = bank_weight + ((size_t)(f * DD + o) * DD + i) * 9;
#pragma unroll
        for (int j = 0; j < 9; ++j) v[j] = fmaf(wf, bw[j], v[j]);
    }

    // style modulation (style varies along input channel i)
    const float sm = 1.0f + style[b * DD + i];
    float ss = 0.f;
#pragma unroll
    for (int j = 0; j < 9; ++j) {
        v[j] *= sm;
        ss = fmaf(v[j], v[j], ss);
    }

    // block reduction of sum-of-squares over 256 threads (per (b,o))
    __shared__ float red[4];
    float tot = ss;
#pragma unroll
    for (int off = 32; off > 0; off >>= 1) tot += __shfl_down(tot, off, 64);
    const int wave = threadIdx.x >> 6;
    const int lane = threadIdx.x & 63;
    if (lane == 0) red[wave] = tot;
    __syncthreads();
    if (threadIdx.x == 0) red[0] = red[0] + red[1] + red[2] + red[3];
    __syncthreads();
    const float norm = rsqrtf(red[0] + 1e-8f);

    float* dst = kflt + ((size_t)(b * DD + o) * DD + i) * 9;
#pragma unroll
    for (int j = 0; j < 9; ++j) dst[j] = v[j] * norm;
}

// ---------------------------------------------------------------------------
// Kernel 2: per-sample 3x3 conv, stride 1, SAME.
// grid = (spatial tile 0..3, o-block 0..31, b 0..7), block = 256.
// Each block: 8 output channels x 32x32 pixels; each thread: 8 o x 4 pixels.
// ---------------------------------------------------------------------------
__global__ __launch_bounds__(256) void conv_kernel(
    const float* __restrict__ x,     // (B, D, 64, 64)
    const float* __restrict__ kflt,  // (B, D, D, 9)
    float* __restrict__ out)         // (B, D, 64, 64)
{
    __shared__ float xs[34][36];     // padded input tile, stride 36 (16B-aligned rows)

    const int tile = blockIdx.x;          // 0..3
    const int ob   = blockIdx.y;          // 0..31
    const int b    = blockIdx.z;          // 0..7
    const int r0 = (tile >> 1) * TS;
    const int c0 = (tile & 1) * TS;
    const int o0 = ob * OT;

    const int t  = threadIdx.x;
    const int tr = t >> 3;                // output row in tile, 0..31
    const int tc = (t & 7) * 4;           // output col in tile, 0,4,..,28

    float acc[OT][4];
#pragma unroll
    for (int oo = 0; oo < OT; ++oo)
#pragma unroll
        for (int p = 0; p < 4; ++p) acc[oo][p] = 0.f;

    const float* xb = x + (size_t)b * DD * HH * WW;
    const float* kb = kflt + (size_t)(b * DD + o0) * DD * 9;

    for (int i = 0; i < DD; ++i) {
        __syncthreads();   // previous iteration finished reading xs
        // stage 34x34 zero-padded tile of x[b][i]
        const float* xp = xb + (size_t)i * HH * WW;
        for (int idx = t; idx < 34 * 34; idx += 256) {
            const int row = idx / 34;
            const int col = idx - row * 34;
            const int gr = r0 - 1 + row;
            const int gc = c0 - 1 + col;
            float val = 0.f;
            if (gr >= 0 && gr < HH && gc >= 0 && gc < WW)
                val = xp[gr * WW + gc];
            xs[row][col] = val;
        }
        __syncthreads();

        // 3 rows x 6 cols of input -> 4 output pixels x 9 taps (sliding window)
        float xv[3][6];
#pragma unroll
        for (int kh = 0; kh < 3; ++kh)
#pragma unroll
            for (int j = 0; j < 6; ++j)
                xv[kh][j] = xs[tr + kh][tc + j];

#pragma unroll
        for (int oo = 0; oo < OT; ++oo) {
            // uniform address -> scalar loads, stays off the LDS/VMEM vector path
            const float* kp = kb + ((size_t)oo * DD + i) * 9;
            float kv[9];
#pragma unroll
            for (int j = 0; j < 9; ++j) kv[j] = kp[j];
#pragma unroll
            for (int kh = 0; kh < 3; ++kh)
#pragma unroll
                for (int kw = 0; kw < 3; ++kw)
#pragma unroll
                    for (int p = 0; p < 4; ++p)
                        acc[oo][p] = fmaf(kv[kh * 3 + kw], xv[kh][p + kw], acc[oo][p]);
        }
    }

    // write 4-pixel rows as float4
#pragma unroll
    for (int oo = 0; oo < OT; ++oo) {
        float* op = out + (((size_t)(b * DD + o0 + oo) * HH) + (r0 + tr)) * WW + (c0 + tc);
        float4 v4 = make_float4(acc[oo][0], acc[oo][1], acc[oo][2], acc[oo][3]);
        *reinterpret_cast<float4*>(op) = v4;
    }
}

extern "C" void kernel_launch(void* const* d_in, const int* in_sizes, int n_in,
                              void* d_out, int out_size, void* d_ws, size_t ws_size,
                              hipStream_t stream) {
    const float* x            = (const float*)d_in[0];  // (8,256,64,64)
    const float* bank_request = (const float*)d_in[1];  // (8,16)
    const float* style        = (const float*)d_in[2];  // (8,1,256,1,1)
    const float* bank_weight  = (const float*)d_in[3];  // (16,256,256,3,3)
    float* out = (float*)d_out;                         // (8,256,64,64)

    float* kflt = (float*)d_ws;  // 8*256*256*9*4 = 18,874,368 bytes

    prep_filter<<<dim3(DD, BB), 256, 0, stream>>>(bank_request, style, bank_weight, kflt);
    conv_kernel<<<dim3(4, DD / OT, BB), 256, 0, stream>>>(x, kflt, out);
}

// Round 2
// 120.271 us; speedup vs baseline: 6.2403x; 6.2403x over previous
//
#include <hip/hip_runtime.h>
#include <hip/hip_bf16.h>
#include <math.h>

#define BB 8
#define FF 16
#define DD 256
#define HH 64
#define WW 64

typedef short bf16x8 __attribute__((ext_vector_type(8)));
typedef float f32x4 __attribute__((ext_vector_type(4)));

__device__ inline ushort f2bf(float f) {
    union { float f; unsigned u; } v; v.f = f;
    unsigned r = v.u + 0x7FFFu + ((v.u >> 16) & 1u);   // RNE
    return (ushort)(r >> 16);
}

// ---------------------------------------------------------------------------
// Kernel 0: cast x fp32 -> bf16 and transpose to xb[b][r][c][i] (i innermost)
// grid = (64 r, 8 b), block = 256
// ---------------------------------------------------------------------------
__global__ __launch_bounds__(256) void cast_x(
    const float* __restrict__ x,   // (B, D, 64, 64)
    ushort* __restrict__ xb)       // (B, 64, 64, D)
{
    __shared__ ushort ls[64][258];   // [c][i], pad 2 -> stride 129 words
    const int r = blockIdx.x, b = blockIdx.y, t = threadIdx.x;

    // phase 1: coalesced float4 reads along c, scatter into ls[c][i]
    const int c4 = (t & 15) * 4;
    const int ig = t >> 4;           // 0..15
#pragma unroll
    for (int j = 0; j < 16; ++j) {
        const int i = ig * 16 + j;
        const float4 xv = *reinterpret_cast<const float4*>(
            x + (((size_t)(b * DD + i) * HH) + r) * WW + c4);
        ls[c4 + 0][i] = f2bf(xv.x);
        ls[c4 + 1][i] = f2bf(xv.y);
        ls[c4 + 2][i] = f2bf(xv.z);
        ls[c4 + 3][i] = f2bf(xv.w);
    }
    __syncthreads();

    // phase 2: read rows of ls coalesced along i, write xb coalesced
    const int i2 = t & 127;          // i-pair
    const int ch = t >> 7;           // 0..1
#pragma unroll
    for (int cl = 0; cl < 32; ++cl) {
        const int c = ch * 32 + cl;
        const unsigned u = (unsigned)ls[c][2 * i2] | ((unsigned)ls[c][2 * i2 + 1] << 16);
        *reinterpret_cast<unsigned*>(xb + (((size_t)(b * HH + r) * WW) + c) * DD + 2 * i2) = u;
    }
}

// ---------------------------------------------------------------------------
// Kernel 1: build per-sample demodulated filters -> bf16 Ak[b][tap][i/8][o][8]
// grid = (o=256, b=8), block = 256 (thread = input channel i)
// ---------------------------------------------------------------------------
__global__ __launch_bounds__(256) void prep_filter(
    const float* __restrict__ bank_request,   // (B, F)
    const float* __restrict__ style,          // (B, 1, D, 1, 1)
    const float* __restrict__ bank_weight,    // (F, D, D, 3, 3)
    ushort* __restrict__ Ak)                  // (B, 9, D/8, D_o, 8) bf16
{
    const int o = blockIdx.x;
    const int b = blockIdx.y;
    const int i = threadIdx.x;   // 0..255

    float wreq[FF];
    float m = -1e30f;
#pragma unroll
    for (int f = 0; f < FF; ++f) {
        wreq[f] = bank_request[b * FF + f];
        m = fmaxf(m, wreq[f]);
    }
    float s = 0.f;
#pragma unroll
    for (int f = 0; f < FF; ++f) {
        wreq[f] = __expf(wreq[f] - m);
        s += wreq[f];
    }
    const float inv = 1.0f / s;

    float v[9];
#pragma unroll
    for (int j = 0; j < 9; ++j) v[j] = 0.f;

#pragma unroll
    for (int f = 0; f < FF; ++f) {
        const float wf = wreq[f] * inv;
        const float* bw = bank_weight + ((size_t)(f * DD + o) * DD + i) * 9;
#pragma unroll
        for (int j = 0; j < 9; ++j) v[j] = fmaf(wf, bw[j], v[j]);
    }

    const float sm = 1.0f + style[b * DD + i];
    float ss = 0.f;
#pragma unroll
    for (int j = 0; j < 9; ++j) {
        v[j] *= sm;
        ss = fmaf(v[j], v[j], ss);
    }

    __shared__ float red[4];
    float tot = ss;
#pragma unroll
    for (int off = 32; off > 0; off >>= 1) tot += __shfl_down(tot, off, 64);
    const int wave = threadIdx.x >> 6;
    const int lane = threadIdx.x & 63;
    if (lane == 0) red[wave] = tot;
    __syncthreads();
    if (threadIdx.x == 0) red[0] = red[0] + red[1] + red[2] + red[3];
    __syncthreads();
    const float norm = rsqrtf(red[0] + 1e-8f);

    // Ak[b][tap][i>>3][o][i&7]
#pragma unroll
    for (int j = 0; j < 9; ++j) {
        const size_t idx = ((((size_t)(b * 9 + j) * 32 + (i >> 3)) * DD) + o) * 8 + (i & 7);
        Ak[idx] = f2bf(v[j] * norm);
    }
}

// ---------------------------------------------------------------------------
// Kernel 2: implicit-GEMM conv via MFMA 16x16x32 bf16.
// grid = (32 rowpairs, 2 o-tiles, 8 b), block = 256 (4 waves, 2x2 wave grid).
// Block tile: 128 o x (2 rows x 64 cols). Wave tile: 64 o x 64 px (4x4 frags).
// ---------------------------------------------------------------------------
__global__ __launch_bounds__(256, 2) void conv_mfma(
    const ushort* __restrict__ xb,   // (B, 64, 64, D) bf16
    const ushort* __restrict__ Ak,   // (B, 9, 32, 256, 8) bf16
    float* __restrict__ out)         // (B, D, 64, 64) fp32
{
    // x tile: [4 rows][66 cells][32 i], 80B cells (64B data + 16B pad)
    __shared__ __align__(16) char xs[4 * 66 * 80];

    const int rp = blockIdx.x, ot = blockIdx.y, b = blockIdx.z;
    const int r0 = rp * 2, o0 = ot * 128;
    const int t = threadIdx.x;
    const int w = t >> 6, l = t & 63;
    const int wm = w >> 1, wn = w & 1;
    const int lo = l & 15, lhi = l >> 4;

    f32x4 acc[4][4];
#pragma unroll
    for (int a = 0; a < 4; ++a)
#pragma unroll
        for (int c = 0; c < 4; ++c)
#pragma unroll
            for (int j = 0; j < 4; ++j) acc[a][c][j] = 0.f;

    const int obase = o0 + wm * 64 + lo;

    for (int kc = 0; kc < 8; ++kc) {
        const int i0 = kc * 32;
        __syncthreads();
        // stage B tile: rows r0-1..r0+2, cols -1..64, 32 input channels
        for (int idx = t; idx < 4 * 66 * 4; idx += 256) {
            const int row = idx / 264;
            const int rem = idx - row * 264;
            const int cell = rem >> 2;
            const int q = rem & 3;
            const int gr = r0 - 1 + row;
            const int gc = cell - 1;
            bf16x8 v = {0, 0, 0, 0, 0, 0, 0, 0};
            if ((unsigned)gr < 64u && (unsigned)gc < 64u)
                v = *reinterpret_cast<const bf16x8*>(
                    xb + (((size_t)(b * HH + gr) * WW) + gc) * DD + i0 + q * 8);
            *reinterpret_cast<bf16x8*>(xs + (row * 66 + cell) * 80 + q * 16) = v;
        }
        __syncthreads();

        const int ib = (i0 >> 3) + lhi;
#pragma unroll
        for (int tap = 0; tap < 9; ++tap) {
            const int dr = tap / 3, dc = tap % 3;     // 0..2 (shift-1, pad+1 cancel)
            bf16x8 bfr[4], afr[4];
            const int rowslot = wn + dr;
#pragma unroll
            for (int fn = 0; fn < 4; ++fn) {
                const int cell = fn * 16 + lo + dc;   // 0..65
                bfr[fn] = *reinterpret_cast<const bf16x8*>(
                    xs + (rowslot * 66 + cell) * 80 + lhi * 16);
            }
#pragma unroll
            for (int fm = 0; fm < 4; ++fm) {
                afr[fm] = *reinterpret_cast<const bf16x8*>(
                    Ak + ((((size_t)(b * 9 + tap) * 32 + ib) * DD) + obase + fm * 16) * 8);
            }
#pragma unroll
            for (int fm = 0; fm < 4; ++fm)
#pragma unroll
                for (int fn = 0; fn < 4; ++fn)
                    acc[fm][fn] = __builtin_amdgcn_mfma_f32_16x16x32_bf16(
                        afr[fm], bfr[fn], acc[fm][fn], 0, 0, 0);
        }
    }

    // epilogue: C/D layout col=lane&15 (px), row=(lane>>4)*4+reg (o)
    const int r_out = r0 + wn;
#pragma unroll
    for (int fm = 0; fm < 4; ++fm) {
#pragma unroll
        for (int fn = 0; fn < 4; ++fn) {
            const int oo = o0 + wm * 64 + fm * 16 + lhi * 4;
            const int cc = fn * 16 + lo;
            float* op = out + (((size_t)(b * DD + oo) * HH) + r_out) * WW + cc;
#pragma unroll
            for (int j = 0; j < 4; ++j) op[(size_t)j * HH * WW] = acc[fm][fn][j];
        }
    }
}

extern "C" void kernel_launch(void* const* d_in, const int* in_sizes, int n_in,
                              void* d_out, int out_size, void* d_ws, size_t ws_size,
                              hipStream_t stream) {
    const float* x            = (const float*)d_in[0];  // (8,256,64,64)
    const float* bank_request = (const float*)d_in[1];  // (8,16)
    const float* style        = (const float*)d_in[2];  // (8,1,256,1,1)
    const float* bank_weight  = (const float*)d_in[3];  // (16,256,256,3,3)
    float* out = (float*)d_out;                         // (8,256,64,64)

    ushort* Ak = (ushort*)d_ws;                         // 8*9*32*256*8 = 4,718,592 elems
    ushort* xb = Ak + (size_t)8 * 9 * 32 * 256 * 8;     // 8*64*64*256 = 8,388,608 elems

    cast_x<<<dim3(HH, BB), 256, 0, stream>>>(x, xb);
    prep_filter<<<dim3(DD, BB), 256, 0, stream>>>(bank_request, style, bank_weight, Ak);
    conv_mfma<<<dim3(32, 2, BB), 256, 0, stream>>>(xb, Ak, out);
}

// Round 3
// 118.891 us; speedup vs baseline: 6.3127x; 1.0116x over previous
//
#include <hip/hip_runtime.h>
#include <hip/hip_bf16.h>
#include <math.h>

#define BB 8
#define FF 16
#define DD 256
#define HH 64
#define WW 64

typedef short bf16x8 __attribute__((ext_vector_type(8)));
typedef float f32x4 __attribute__((ext_vector_type(4)));

__device__ inline ushort f2bf(float f) {
    union { float f; unsigned u; } v; v.f = f;
    unsigned r = v.u + 0x7FFFu + ((v.u >> 16) & 1u);   // RNE
    return (ushort)(r >> 16);
}

// ---------------------------------------------------------------------------
// Kernel 0: cast x fp32 -> bf16, transpose to xb[b][r][c][i] (i innermost)
// ---------------------------------------------------------------------------
__global__ __launch_bounds__(256) void cast_x(
    const float* __restrict__ x,   // (B, D, 64, 64)
    ushort* __restrict__ xb)       // (B, 64, 64, D)
{
    __shared__ ushort ls[64][258];
    const int r = blockIdx.x, b = blockIdx.y, t = threadIdx.x;

    const int c4 = (t & 15) * 4;
    const int ig = t >> 4;
#pragma unroll
    for (int j = 0; j < 16; ++j) {
        const int i = ig * 16 + j;
        const float4 xv = *reinterpret_cast<const float4*>(
            x + (((size_t)(b * DD + i) * HH) + r) * WW + c4);
        ls[c4 + 0][i] = f2bf(xv.x);
        ls[c4 + 1][i] = f2bf(xv.y);
        ls[c4 + 2][i] = f2bf(xv.z);
        ls[c4 + 3][i] = f2bf(xv.w);
    }
    __syncthreads();

    const int i2 = t & 127;
    const int ch = t >> 7;
#pragma unroll
    for (int cl = 0; cl < 32; ++cl) {
        const int c = ch * 32 + cl;
        const unsigned u = (unsigned)ls[c][2 * i2] | ((unsigned)ls[c][2 * i2 + 1] << 16);
        *reinterpret_cast<unsigned*>(xb + (((size_t)(b * HH + r) * WW) + c) * DD + 2 * i2) = u;
    }
}

// ---------------------------------------------------------------------------
// Kernel 1: filters for ALL batches in one pass over bank_weight.
// grid = (o=256), block = 256 (thread = input channel i).
// Ak[b][i/8][o][tap][8] bf16  (all 9 taps contiguous per (i-block, o))
// ---------------------------------------------------------------------------
__global__ __launch_bounds__(256) void prep_filter(
    const float* __restrict__ bank_request,   // (B, F)
    const float* __restrict__ style,          // (B, 1, D, 1, 1)
    const float* __restrict__ bank_weight,    // (F, D, D, 3, 3)
    ushort* __restrict__ Ak)                  // (B, 32, 256, 9, 8)
{
    const int o = blockIdx.x;
    const int i = threadIdx.x;

    __shared__ float wsm[BB][FF];
    __shared__ float red[4][BB];
    __shared__ float nrm[BB];

    if (i < BB) {
        float v[FF];
        float m = -1e30f;
#pragma unroll
        for (int f = 0; f < FF; ++f) {
            v[f] = bank_request[i * FF + f];
            m = fmaxf(m, v[f]);
        }
        float s = 0.f;
#pragma unroll
        for (int f = 0; f < FF; ++f) { v[f] = __expf(v[f] - m); s += v[f]; }
        const float inv = 1.0f / s;
#pragma unroll
        for (int f = 0; f < FF; ++f) wsm[i][f] = v[f] * inv;
    }
    __syncthreads();

    float acc9[BB][9];
#pragma unroll
    for (int b = 0; b < BB; ++b)
#pragma unroll
        for (int j = 0; j < 9; ++j) acc9[b][j] = 0.f;

    // 2-deep prefetch over f
    float pre[2][9];
#pragma unroll
    for (int s = 0; s < 2; ++s) {
        const float* p = bank_weight + ((size_t)(s * DD + o) * DD + i) * 9;
#pragma unroll
        for (int j = 0; j < 9; ++j) pre[s][j] = p[j];
    }
#pragma unroll
    for (int f = 0; f < FF; ++f) {
        const int sl = f & 1;
        float cur[9];
#pragma unroll
        for (int j = 0; j < 9; ++j) cur[j] = pre[sl][j];
        if (f + 2 < FF) {
            const float* p = bank_weight + ((size_t)((f + 2) * DD + o) * DD + i) * 9;
#pragma unroll
            for (int j = 0; j < 9; ++j) pre[sl][j] = p[j];
        }
#pragma unroll
        for (int b = 0; b < BB; ++b) {
            const float wf = wsm[b][f];
#pragma unroll
            for (int j = 0; j < 9; ++j) acc9[b][j] = fmaf(wf, cur[j], acc9[b][j]);
        }
    }

    // style modulation + per-thread sum of squares
    float ss[BB];
#pragma unroll
    for (int b = 0; b < BB; ++b) {
        const float sm = 1.0f + style[b * DD + i];
        float t = 0.f;
#pragma unroll
        for (int j = 0; j < 9; ++j) {
            acc9[b][j] *= sm;
            t = fmaf(acc9[b][j], acc9[b][j], t);
        }
        ss[b] = t;
    }

    // block reduction per b
    const int wave = i >> 6, lane = i & 63;
#pragma unroll
    for (int b = 0; b < BB; ++b) {
        float tv = ss[b];
#pragma unroll
        for (int off = 32; off > 0; off >>= 1) tv += __shfl_down(tv, off, 64);
        if (lane == 0) red[wave][b] = tv;
    }
    __syncthreads();
    if (i < BB)
        nrm[i] = rsqrtf(red[0][i] + red[1][i] + red[2][i] + red[3][i] + 1e-8f);
    __syncthreads();

    const int ib = i >> 3, e = i & 7;
#pragma unroll
    for (int b = 0; b < BB; ++b) {
        const float nb = nrm[b];
        ushort* dst = Ak + (((size_t)(b * 32 + ib) * DD + o) * 9) * 8 + e;
#pragma unroll
        for (int j = 0; j < 9; ++j) dst[j * 8] = f2bf(acc9[b][j] * nb);
    }
}

// ---------------------------------------------------------------------------
// Kernel 2: implicit-GEMM conv, MFMA 16x16x32 bf16, double-buffered LDS,
// async-stage split + 2-deep A/B fragment pipeline.
// grid = (32 rowpairs, 2 o-tiles, 8 b), block = 256 (2x2 waves).
// ---------------------------------------------------------------------------
#define XS_BUF 21120   // 4 rows * 66 cells * 80 B

__global__ __launch_bounds__(256, 2) void conv_mfma(
    const ushort* __restrict__ xb,   // (B, 64, 64, D) bf16
    const ushort* __restrict__ Ak,   // (B, 32, 256, 9, 8) bf16
    float* __restrict__ out)         // (B, D, 64, 64) fp32
{
    __shared__ __align__(16) char xs[2 * XS_BUF];

    const int rp = blockIdx.x, ot = blockIdx.y, b = blockIdx.z;
    const int r0 = rp * 2, o0 = ot * 128;
    const int t = threadIdx.x;
    const int w = t >> 6, l = t & 63;
    const int wm = w >> 1, wn = w & 1;
    const int lo = l & 15, lhi = l >> 4;

    // ---- per-thread staging descriptors (1056 16B chunks) ----
    const ushort* sg_ptr[5];
    int sg_lds[5];
    bool sg_ok[5];
#pragma unroll
    for (int s = 0; s < 5; ++s) {
        const int idx = t + s * 256;
        const bool active = (s < 4) || (t < 32);
        const int row = idx / 264;
        const int rem = idx - row * 264;
        const int cell = rem >> 2;
        const int q = rem & 3;
        const int gr = r0 - 1 + row;
        const int gc = cell - 1;
        sg_ok[s] = active && ((unsigned)gr < 64u) && ((unsigned)gc < 64u);
        sg_ptr[s] = xb + (((size_t)(b * HH + (gr & 63)) * WW) + (gc & 63)) * DD + q * 8;
        sg_lds[s] = (row * 66 + cell) * 80 + q * 16;
    }
    const bool sg_act4 = (t < 32);

    f32x4 acc[4][4];
#pragma unroll
    for (int a = 0; a < 4; ++a)
#pragma unroll
        for (int c = 0; c < 4; ++c)
#pragma unroll
            for (int j = 0; j < 4; ++j) acc[a][c][j] = 0.f;

    const int obase = o0 + wm * 64 + lo;
    // per-lane fixed LDS offset for B fragments
    const int bLaneOff = (wn * 66 + lo) * 80 + lhi * 16;

    bf16x8 vr[5];
    bf16x8 aF[2][4], bF[2][4];

    // prologue: stage chunk 0
#pragma unroll
    for (int s = 0; s < 5; ++s) {
        bf16x8 v = {0, 0, 0, 0, 0, 0, 0, 0};
        if (sg_ok[s]) v = *reinterpret_cast<const bf16x8*>(sg_ptr[s]);
        vr[s] = v;
    }
#pragma unroll
    for (int s = 0; s < 5; ++s)
        if (s < 4 || sg_act4)
            *reinterpret_cast<bf16x8*>(xs + sg_lds[s]) = vr[s];
    __syncthreads();

#define LDFRAG(tp, sl, bufc, aln)  do {                                        \
        const int dr_ = (tp) / 3, dc_ = (tp) % 3;                              \
        const char* bb_ = (bufc) + (dr_ * 66 + dc_) * 80;                      \
        bF[sl][0] = *reinterpret_cast<const bf16x8*>(bb_ + 0 * 1280);          \
        bF[sl][1] = *reinterpret_cast<const bf16x8*>(bb_ + 1 * 1280);          \
        bF[sl][2] = *reinterpret_cast<const bf16x8*>(bb_ + 2 * 1280);          \
        bF[sl][3] = *reinterpret_cast<const bf16x8*>(bb_ + 3 * 1280);          \
        aF[sl][0] = *reinterpret_cast<const bf16x8*>((aln) + 0 * 1152 + (tp) * 8); \
        aF[sl][1] = *reinterpret_cast<const bf16x8*>((aln) + 1 * 1152 + (tp) * 8); \
        aF[sl][2] = *reinterpret_cast<const bf16x8*>((aln) + 2 * 1152 + (tp) * 8); \
        aF[sl][3] = *reinterpret_cast<const bf16x8*>((aln) + 3 * 1152 + (tp) * 8); \
    } while (0)

    for (int kc = 0; kc < 8; ++kc) {
        const int cur = kc & 1;

        // stage next chunk's x into registers (latency hides under MFMA)
        if (kc < 7) {
            const int ioff = (kc + 1) * 32;
#pragma unroll
            for (int s = 0; s < 5; ++s) {
                bf16x8 v = {0, 0, 0, 0, 0, 0, 0, 0};
                if (sg_ok[s]) v = *reinterpret_cast<const bf16x8*>(sg_ptr[s] + ioff);
                vr[s] = v;
            }
        }

        // compute on buf[cur]
        const char* bufc = xs + cur * XS_BUF + bLaneOff;
        const int ib = kc * 4 + lhi;
        const ushort* aLane = Ak + (((size_t)(b * 32 + ib) * DD + obase) * 9) * 8;

        LDFRAG(0, 0, bufc, aLane);
#pragma unroll
        for (int tap = 0; tap < 9; ++tap) {
            const int cs = tap & 1;
            if (tap < 8) LDFRAG(tap + 1, cs ^ 1, bufc, aLane);
#pragma unroll
            for (int fm = 0; fm < 4; ++fm)
#pragma unroll
                for (int fn = 0; fn < 4; ++fn)
                    acc[fm][fn] = __builtin_amdgcn_mfma_f32_16x16x32_bf16(
                        aF[cs][fm], bF[cs][fn], acc[fm][fn], 0, 0, 0);
        }

        // write staged chunk to the other buffer
        if (kc < 7) {
            char* dstb = xs + (cur ^ 1) * XS_BUF;
#pragma unroll
            for (int s = 0; s < 5; ++s)
                if (s < 4 || sg_act4)
                    *reinterpret_cast<bf16x8*>(dstb + sg_lds[s]) = vr[s];
        }
        __syncthreads();
    }
#undef LDFRAG

    // epilogue: C/D layout col=lane&15 (px), row=(lane>>4)*4+reg (o)
    const int r_out = r0 + wn;
#pragma unroll
    for (int fm = 0; fm < 4; ++fm) {
#pragma unroll
        for (int fn = 0; fn < 4; ++fn) {
            const int oo = o0 + wm * 64 + fm * 16 + lhi * 4;
            const int cc = fn * 16 + lo;
            float* op = out + (((size_t)(b * DD + oo) * HH) + r_out) * WW + cc;
#pragma unroll
            for (int j = 0; j < 4; ++j) op[(size_t)j * HH * WW] = acc[fm][fn][j];
        }
    }
}

extern "C" void kernel_launch(void* const* d_in, const int* in_sizes, int n_in,
                              void* d_out, int out_size, void* d_ws, size_t ws_size,
                              hipStream_t stream) {
    const float* x            = (const float*)d_in[0];  // (8,256,64,64)
    const float* bank_request = (const float*)d_in[1];  // (8,16)
    const float* style        = (const float*)d_in[2];  // (8,1,256,1,1)
    const float* bank_weight  = (const float*)d_in[3];  // (16,256,256,3,3)
    float* out = (float*)d_out;                         // (8,256,64,64)

    ushort* Ak = (ushort*)d_ws;                         // 8*32*256*9*8 = 4,718,592 elems
    ushort* xb = Ak + (size_t)8 * 32 * 256 * 9 * 8;     // 8*64*64*256 = 8,388,608 elems

    cast_x<<<dim3(HH, BB), 256, 0, stream>>>(x, xb);
    prep_filter<<<dim3(DD), 256, 0, stream>>>(bank_request, style, bank_weight, Ak);
    conv_mfma<<<dim3(32, 2, BB), 256, 0, stream>>>(xb, Ak, out);
}

// Round 4
// 88.478 us; speedup vs baseline: 8.4826x; 1.3437x over previous
//
#include <hip/hip_runtime.h>
#include <hip/hip_bf16.h>
#include <math.h>

#define BB 8
#define FF 16
#define DD 256
#define HH 64
#define WW 64

typedef short bf16x8 __attribute__((ext_vector_type(8)));
typedef float f32x4 __attribute__((ext_vector_type(4)));

__device__ inline ushort f2bf(float f) {
    union { float f; unsigned u; } v; v.f = f;
    unsigned r = v.u + 0x7FFFu + ((v.u >> 16) & 1u);   // RNE
    return (ushort)(r >> 16);
}

// ---------------------------------------------------------------------------
// Kernel 0: cast x fp32 -> bf16, transpose to xb[b][r][c][i] (i innermost)
// ---------------------------------------------------------------------------
__global__ __launch_bounds__(256) void cast_x(
    const float* __restrict__ x,   // (B, D, 64, 64)
    ushort* __restrict__ xb)       // (B, 64, 64, D)
{
    __shared__ ushort ls[64][258];
    const int r = blockIdx.x, b = blockIdx.y, t = threadIdx.x;

    const int c4 = (t & 15) * 4;
    const int ig = t >> 4;
#pragma unroll
    for (int j = 0; j < 16; ++j) {
        const int i = ig * 16 + j;
        const float4 xv = *reinterpret_cast<const float4*>(
            x + (((size_t)(b * DD + i) * HH) + r) * WW + c4);
        ls[c4 + 0][i] = f2bf(xv.x);
        ls[c4 + 1][i] = f2bf(xv.y);
        ls[c4 + 2][i] = f2bf(xv.z);
        ls[c4 + 3][i] = f2bf(xv.w);
    }
    __syncthreads();

    const int i2 = t & 127;
    const int ch = t >> 7;
#pragma unroll
    for (int cl = 0; cl < 32; ++cl) {
        const int c = ch * 32 + cl;
        const unsigned u = (unsigned)ls[c][2 * i2] | ((unsigned)ls[c][2 * i2 + 1] << 16);
        *reinterpret_cast<unsigned*>(xb + (((size_t)(b * HH + r) * WW) + c) * DD + 2 * i2) = u;
    }
}

// ---------------------------------------------------------------------------
// Kernel 1: filters for ALL batches in one pass over bank_weight.
// grid = (o=256), block = 256 (thread = input channel i).
// Ak[b][tap][i/8][o][8] bf16  (coalesced A-fragment loads in conv)
// ---------------------------------------------------------------------------
__global__ __launch_bounds__(256) void prep_filter(
    const float* __restrict__ bank_request,   // (B, F)
    const float* __restrict__ style,          // (B, 1, D, 1, 1)
    const float* __restrict__ bank_weight,    // (F, D, D, 3, 3)
    ushort* __restrict__ Ak)                  // (B, 9, 32, 256, 8)
{
    const int o = blockIdx.x;
    const int i = threadIdx.x;

    __shared__ float wsm[BB][FF];
    __shared__ float red[4][BB];
    __shared__ float nrm[BB];

    if (i < BB) {
        float v[FF];
        float m = -1e30f;
#pragma unroll
        for (int f = 0; f < FF; ++f) {
            v[f] = bank_request[i * FF + f];
            m = fmaxf(m, v[f]);
        }
        float s = 0.f;
#pragma unroll
        for (int f = 0; f < FF; ++f) { v[f] = __expf(v[f] - m); s += v[f]; }
        const float inv = 1.0f / s;
#pragma unroll
        for (int f = 0; f < FF; ++f) wsm[i][f] = v[f] * inv;
    }
    __syncthreads();

    float acc9[BB][9];
#pragma unroll
    for (int b = 0; b < BB; ++b)
#pragma unroll
        for (int j = 0; j < 9; ++j) acc9[b][j] = 0.f;

    float pre[2][9];
#pragma unroll
    for (int s = 0; s < 2; ++s) {
        const float* p = bank_weight + ((size_t)(s * DD + o) * DD + i) * 9;
#pragma unroll
        for (int j = 0; j < 9; ++j) pre[s][j] = p[j];
    }
#pragma unroll
    for (int f = 0; f < FF; ++f) {
        const int sl = f & 1;
        float cur[9];
#pragma unroll
        for (int j = 0; j < 9; ++j) cur[j] = pre[sl][j];
        if (f + 2 < FF) {
            const float* p = bank_weight + ((size_t)((f + 2) * DD + o) * DD + i) * 9;
#pragma unroll
            for (int j = 0; j < 9; ++j) pre[sl][j] = p[j];
        }
#pragma unroll
        for (int b = 0; b < BB; ++b) {
            const float wf = wsm[b][f];
#pragma unroll
            for (int j = 0; j < 9; ++j) acc9[b][j] = fmaf(wf, cur[j], acc9[b][j]);
        }
    }

    float ss[BB];
#pragma unroll
    for (int b = 0; b < BB; ++b) {
        const float sm = 1.0f + style[b * DD + i];
        float t = 0.f;
#pragma unroll
        for (int j = 0; j < 9; ++j) {
            acc9[b][j] *= sm;
            t = fmaf(acc9[b][j], acc9[b][j], t);
        }
        ss[b] = t;
    }

    const int wave = i >> 6, lane = i & 63;
#pragma unroll
    for (int b = 0; b < BB; ++b) {
        float tv = ss[b];
#pragma unroll
        for (int off = 32; off > 0; off >>= 1) tv += __shfl_down(tv, off, 64);
        if (lane == 0) red[wave][b] = tv;
    }
    __syncthreads();
    if (i < BB)
        nrm[i] = rsqrtf(red[0][i] + red[1][i] + red[2][i] + red[3][i] + 1e-8f);
    __syncthreads();

    const int ib = i >> 3, e = i & 7;
#pragma unroll
    for (int b = 0; b < BB; ++b) {
        const float nb = nrm[b];
#pragma unroll
        for (int j = 0; j < 9; ++j) {
            const size_t idx = ((((size_t)(b * 9 + j) * 32 + ib) * DD) + o) * 8 + e;
            Ak[idx] = f2bf(acc9[b][j] * nb);
        }
    }
}

// ---------------------------------------------------------------------------
// Kernel 2: implicit-GEMM conv, MFMA 16x16x32 bf16.
// grid = (32 rowpairs, 2 o-tiles, 8 b), block = 512 (8 waves).
// Block tile: 128 o x (2 rows x 64 cols). Wave: 64 o x 32 px (4x2 frags).
// 16 waves/CU (50% occupancy cap) vs 8 before -> latency hiding via TLP.
// ---------------------------------------------------------------------------
__global__ __launch_bounds__(512, 4) void conv_mfma(
    const ushort* __restrict__ xb,   // (B, 64, 64, D) bf16
    const ushort* __restrict__ Ak,   // (B, 9, 32, 256, 8) bf16
    float* __restrict__ out)         // (B, D, 64, 64) fp32
{
    // x tile: [4 rows][66 cells][32 i], 80B cells (64B data + 16B pad, 2-way banks)
    __shared__ __align__(16) char xs[4 * 66 * 80];

    const int rp = blockIdx.x, ot = blockIdx.y, b = blockIdx.z;
    const int r0 = rp * 2, o0 = ot * 128;
    const int t = threadIdx.x;
    const int w = t >> 6, l = t & 63;
    const int wm = w >> 2;          // o half (0,1)
    const int wn = (w >> 1) & 1;    // row (0,1)
    const int wp = w & 1;           // col half (0,1)
    const int lo = l & 15, lhi = l >> 4;

    // staging descriptors: 1056 16B chunks over 512 threads (3 slots)
    const ushort* sg_ptr[3];
    int sg_lds[3];
    bool sg_ok[3];
#pragma unroll
    for (int s = 0; s < 3; ++s) {
        const int idx = t + s * 512;
        const bool active = (s < 2) || (t < 32);
        const int row = idx / 264;
        const int rem = idx - row * 264;
        const int cell = rem >> 2;
        const int q = rem & 3;
        const int gr = r0 - 1 + row;
        const int gc = cell - 1;
        sg_ok[s] = active && ((unsigned)gr < 64u) && ((unsigned)gc < 64u);
        sg_ptr[s] = xb + (((size_t)(b * HH + (gr & 63)) * WW) + (gc & 63)) * DD + q * 8;
        sg_lds[s] = (row * 66 + cell) * 80 + q * 16;
    }
    const bool sg_act2 = (t < 32);

    f32x4 acc[4][2];
#pragma unroll
    for (int a = 0; a < 4; ++a)
#pragma unroll
        for (int c = 0; c < 2; ++c)
#pragma unroll
            for (int j = 0; j < 4; ++j) acc[a][c][j] = 0.f;

    const int obase = o0 + wm * 64 + lo;
    const int bBase = (wp * 32 + lo) * 80 + lhi * 16;

    bf16x8 aF[2][4], bF[2][2];

#define LDFRAG(tp, sl, aB)  do {                                               \
        const int dr_ = (tp) / 3, dc_ = (tp) % 3;                              \
        const char* bb_ = xs + bBase + (((wn + dr_) * 66 + dc_) * 80);         \
        bF[sl][0] = *reinterpret_cast<const bf16x8*>(bb_);                     \
        bF[sl][1] = *reinterpret_cast<const bf16x8*>(bb_ + 1280);              \
        const ushort* ap_ = (aB) + (size_t)(tp) * 65536;                       \
        aF[sl][0] = *reinterpret_cast<const bf16x8*>(ap_);                     \
        aF[sl][1] = *reinterpret_cast<const bf16x8*>(ap_ + 128);               \
        aF[sl][2] = *reinterpret_cast<const bf16x8*>(ap_ + 256);               \
        aF[sl][3] = *reinterpret_cast<const bf16x8*>(ap_ + 384);               \
    } while (0)

    for (int kc = 0; kc < 8; ++kc) {
        __syncthreads();   // previous iteration's reads of xs done
#pragma unroll
        for (int s = 0; s < 3; ++s) {
            if (s < 2 || sg_act2) {
                bf16x8 v = {0, 0, 0, 0, 0, 0, 0, 0};
                if (sg_ok[s]) v = *reinterpret_cast<const bf16x8*>(sg_ptr[s] + kc * 32);
                *reinterpret_cast<bf16x8*>(xs + sg_lds[s]) = v;
            }
        }
        __syncthreads();

        const int ib = kc * 4 + lhi;
        const ushort* aBase = Ak + (((size_t)b * 9 * 32 + ib) * DD + obase) * 8;

        LDFRAG(0, 0, aBase);
#pragma unroll
        for (int tap = 0; tap < 9; ++tap) {
            const int cs = tap & 1;
            if (tap < 8) LDFRAG(tap + 1, cs ^ 1, aBase);
#pragma unroll
            for (int fm = 0; fm < 4; ++fm)
#pragma unroll
                for (int fn = 0; fn < 2; ++fn)
                    acc[fm][fn] = __builtin_amdgcn_mfma_f32_16x16x32_bf16(
                        aF[cs][fm], bF[cs][fn], acc[fm][fn], 0, 0, 0);
        }
    }
#undef LDFRAG

    // epilogue: C/D layout col=lane&15 (px), row=(lane>>4)*4+reg (o)
    const int r_out = r0 + wn;
#pragma unroll
    for (int fm = 0; fm < 4; ++fm) {
#pragma unroll
        for (int fn = 0; fn < 2; ++fn) {
            const int oo = o0 + wm * 64 + fm * 16 + lhi * 4;
            const int cc = wp * 32 + fn * 16 + lo;
            float* op = out + (((size_t)(b * DD + oo) * HH) + r_out) * WW + cc;
#pragma unroll
            for (int j = 0; j < 4; ++j) op[(size_t)j * HH * WW] = acc[fm][fn][j];
        }
    }
}

extern "C" void kernel_launch(void* const* d_in, const int* in_sizes, int n_in,
                              void* d_out, int out_size, void* d_ws, size_t ws_size,
                              hipStream_t stream) {
    const float* x            = (const float*)d_in[0];  // (8,256,64,64)
    const float* bank_request = (const float*)d_in[1];  // (8,16)
    const float* style        = (const float*)d_in[2];  // (8,1,256,1,1)
    const float* bank_weight  = (const float*)d_in[3];  // (16,256,256,3,3)
    float* out = (float*)d_out;                         // (8,256,64,64)

    ushort* Ak = (ushort*)d_ws;                         // 8*9*32*256*8 = 4,718,592 elems
    ushort* xb = Ak + (size_t)8 * 9 * 32 * 256 * 8;     // 8*64*64*256 = 8,388,608 elems

    cast_x<<<dim3(HH, BB), 256, 0, stream>>>(x, xb);
    prep_filter<<<dim3(DD), 256, 0, stream>>>(bank_request, style, bank_weight, Ak);
    conv_mfma<<<dim3(32, 2, BB), 512, 0, stream>>>(xb, Ak, out);
}

// Round 5
// 66.459 us; speedup vs baseline: 11.2929x; 1.3313x over previous
//
#include <hip/hip_runtime.h>
#include <hip/hip_bf16.h>
#include <math.h>

#define BB 8
#define FF 16
#define DD 256
#define HH 64
#define WW 64

typedef short bf16x8 __attribute__((ext_vector_type(8)));
typedef float f32x4 __attribute__((ext_vector_type(4)));

__device__ inline ushort f2bf(float f) {
    union { float f; unsigned u; } v; v.f = f;
    unsigned r = v.u + 0x7FFFu + ((v.u >> 16) & 1u);   // RNE
    return (ushort)(r >> 16);
}

// ---------------------------------------------------------------------------
// Kernel 0: cast x fp32 -> bf16, transpose to xb[b][r][c][i] (i innermost)
// ---------------------------------------------------------------------------
__global__ __launch_bounds__(256) void cast_x(
    const float* __restrict__ x,   // (B, D, 64, 64)
    ushort* __restrict__ xb)       // (B, 64, 64, D)
{
    __shared__ ushort ls[64][258];
    const int r = blockIdx.x, b = blockIdx.y, t = threadIdx.x;

    const int c4 = (t & 15) * 4;
    const int ig = t >> 4;
#pragma unroll
    for (int j = 0; j < 16; ++j) {
        const int i = ig * 16 + j;
        const float4 xv = *reinterpret_cast<const float4*>(
            x + (((size_t)(b * DD + i) * HH) + r) * WW + c4);
        ls[c4 + 0][i] = f2bf(xv.x);
        ls[c4 + 1][i] = f2bf(xv.y);
        ls[c4 + 2][i] = f2bf(xv.z);
        ls[c4 + 3][i] = f2bf(xv.w);
    }
    __syncthreads();

    const int i2 = t & 127;
    const int ch = t >> 7;
#pragma unroll
    for (int cl = 0; cl < 32; ++cl) {
        const int c = ch * 32 + cl;
        const unsigned u = (unsigned)ls[c][2 * i2] | ((unsigned)ls[c][2 * i2 + 1] << 16);
        *reinterpret_cast<unsigned*>(xb + (((size_t)(b * HH + r) * WW) + c) * DD + 2 * i2) = u;
    }
}

// ---------------------------------------------------------------------------
// Kernel 1: filters for ALL batches in one pass over bank_weight.
// Ak[b][tap][i/8][o][8] bf16  (coalesced A-fragment loads in conv)
// ---------------------------------------------------------------------------
__global__ __launch_bounds__(256) void prep_filter(
    const float* __restrict__ bank_request,   // (B, F)
    const float* __restrict__ style,          // (B, 1, D, 1, 1)
    const float* __restrict__ bank_weight,    // (F, D, D, 3, 3)
    ushort* __restrict__ Ak)                  // (B, 9, 32, 256, 8)
{
    const int o = blockIdx.x;
    const int i = threadIdx.x;

    __shared__ float wsm[BB][FF];
    __shared__ float red[4][BB];
    __shared__ float nrm[BB];

    if (i < BB) {
        float v[FF];
        float m = -1e30f;
#pragma unroll
        for (int f = 0; f < FF; ++f) {
            v[f] = bank_request[i * FF + f];
            m = fmaxf(m, v[f]);
        }
        float s = 0.f;
#pragma unroll
        for (int f = 0; f < FF; ++f) { v[f] = __expf(v[f] - m); s += v[f]; }
        const float inv = 1.0f / s;
#pragma unroll
        for (int f = 0; f < FF; ++f) wsm[i][f] = v[f] * inv;
    }
    __syncthreads();

    float acc9[BB][9];
#pragma unroll
    for (int b = 0; b < BB; ++b)
#pragma unroll
        for (int j = 0; j < 9; ++j) acc9[b][j] = 0.f;

    float pre[2][9];
#pragma unroll
    for (int s = 0; s < 2; ++s) {
        const float* p = bank_weight + ((size_t)(s * DD + o) * DD + i) * 9;
#pragma unroll
        for (int j = 0; j < 9; ++j) pre[s][j] = p[j];
    }
#pragma unroll
    for (int f = 0; f < FF; ++f) {
        const int sl = f & 1;
        float cur[9];
#pragma unroll
        for (int j = 0; j < 9; ++j) cur[j] = pre[sl][j];
        if (f + 2 < FF) {
            const float* p = bank_weight + ((size_t)((f + 2) * DD + o) * DD + i) * 9;
#pragma unroll
            for (int j = 0; j < 9; ++j) pre[sl][j] = p[j];
        }
#pragma unroll
        for (int b = 0; b < BB; ++b) {
            const float wf = wsm[b][f];
#pragma unroll
            for (int j = 0; j < 9; ++j) acc9[b][j] = fmaf(wf, cur[j], acc9[b][j]);
        }
    }

    float ss[BB];
#pragma unroll
    for (int b = 0; b < BB; ++b) {
        const float sm = 1.0f + style[b * DD + i];
        float t = 0.f;
#pragma unroll
        for (int j = 0; j < 9; ++j) {
            acc9[b][j] *= sm;
            t = fmaf(acc9[b][j], acc9[b][j], t);
        }
        ss[b] = t;
    }

    const int wave = i >> 6, lane = i & 63;
#pragma unroll
    for (int b = 0; b < BB; ++b) {
        float tv = ss[b];
#pragma unroll
        for (int off = 32; off > 0; off >>= 1) tv += __shfl_down(tv, off, 64);
        if (lane == 0) red[wave][b] = tv;
    }
    __syncthreads();
    if (i < BB)
        nrm[i] = rsqrtf(red[0][i] + red[1][i] + red[2][i] + red[3][i] + 1e-8f);
    __syncthreads();

    const int ib = i >> 3, e = i & 7;
#pragma unroll
    for (int b = 0; b < BB; ++b) {
        const float nb = nrm[b];
#pragma unroll
        for (int j = 0; j < 9; ++j) {
            const size_t idx = ((((size_t)(b * 9 + j) * 32 + ib) * DD) + o) * 8 + e;
            Ak[idx] = f2bf(acc9[b][j] * nb);
        }
    }
}

// ---------------------------------------------------------------------------
// Kernel 2: implicit-GEMM conv, MFMA 16x16x32 bf16.
// grid = (16 rowgroups, 2 o-tiles, 8 b) = 256 blocks (1/CU), block = 512.
// Block tile: 128 o x (4 rows x 64 cols). Wave: 64 o x 64 px (4x4 frags).
// A: global (L2) with 3-slot tap pipeline. B: LDS, double-buffered,
// ONE barrier per K-chunk (reg-staged async split).
// ---------------------------------------------------------------------------
#define XROWS 6
#define XCELLS 66
#define XCELLB 80
#define XBUF (XROWS * XCELLS * XCELLB)   // 31680 B

__global__ __launch_bounds__(512, 2) void conv_mfma(
    const ushort* __restrict__ xb,   // (B, 64, 64, D) bf16
    const ushort* __restrict__ Ak,   // (B, 9, 32, 256, 8) bf16
    float* __restrict__ out)         // (B, D, 64, 64) fp32
{
    __shared__ __align__(16) char xs[2 * XBUF];   // 63360 B

    const int rg = blockIdx.x, ot = blockIdx.y, b = blockIdx.z;
    const int r0 = rg * 4, o0 = ot * 128;
    const int t = threadIdx.x;
    const int w = t >> 6, l = t & 63;
    const int wm = w >> 2;          // o half (0,1)
    const int wn = w & 3;           // row within block tile (0..3)
    const int lo = l & 15, lhi = l >> 4;

    // staging descriptors: 6 rows * 66 cells * 4 q = 1584 16B chunks, 4 slots
    const ushort* sg_ptr[4];
    int sg_lds[4];
    bool sg_ok[4];
    bool sg_act[4];
#pragma unroll
    for (int s = 0; s < 4; ++s) {
        const int idx = t + s * 512;
        sg_act[s] = idx < XROWS * XCELLS * 4;
        const int row = idx / (XCELLS * 4);
        const int rem = idx - row * (XCELLS * 4);
        const int cell = rem >> 2;
        const int q = rem & 3;
        const int gr = r0 - 1 + row;
        const int gc = cell - 1;
        sg_ok[s] = sg_act[s] && ((unsigned)gr < 64u) && ((unsigned)gc < 64u);
        sg_ptr[s] = xb + (((size_t)(b * HH + (gr & 63)) * WW) + (gc & 63)) * DD + q * 8;
        sg_lds[s] = (row * XCELLS + cell) * XCELLB + q * 16;
    }

    f32x4 acc[4][4];
#pragma unroll
    for (int a = 0; a < 4; ++a)
#pragma unroll
        for (int c = 0; c < 4; ++c)
#pragma unroll
            for (int j = 0; j < 4; ++j) acc[a][c][j] = 0.f;

    const int obase = o0 + wm * 64 + lo;
    const int bLane = lo * XCELLB + lhi * 16;

    bf16x8 vr[4];
    bf16x8 aF[3][4], bF[2][4];

#define LDA(tp, sl, aB)  do {                                                  \
        const ushort* ap_ = (aB) + (size_t)(tp) * 65536;                       \
        aF[sl][0] = *reinterpret_cast<const bf16x8*>(ap_);                     \
        aF[sl][1] = *reinterpret_cast<const bf16x8*>(ap_ + 128);               \
        aF[sl][2] = *reinterpret_cast<const bf16x8*>(ap_ + 256);               \
        aF[sl][3] = *reinterpret_cast<const bf16x8*>(ap_ + 384);               \
    } while (0)

#define LDB(tp, sl, bufc)  do {                                                \
        const int dr_ = (tp) / 3, dc_ = (tp) % 3;                              \
        const char* bb_ = (bufc) + ((wn + dr_) * XCELLS + dc_) * XCELLB;       \
        bF[sl][0] = *reinterpret_cast<const bf16x8*>(bb_);                     \
        bF[sl][1] = *reinterpret_cast<const bf16x8*>(bb_ + 16 * XCELLB);       \
        bF[sl][2] = *reinterpret_cast<const bf16x8*>(bb_ + 32 * XCELLB);       \
        bF[sl][3] = *reinterpret_cast<const bf16x8*>(bb_ + 48 * XCELLB);       \
    } while (0)

    // prologue: stage chunk 0 into buffer 0
#pragma unroll
    for (int s = 0; s < 4; ++s) {
        bf16x8 v = {0, 0, 0, 0, 0, 0, 0, 0};
        if (sg_ok[s]) v = *reinterpret_cast<const bf16x8*>(sg_ptr[s]);
        vr[s] = v;
    }
#pragma unroll
    for (int s = 0; s < 4; ++s)
        if (sg_act[s]) *reinterpret_cast<bf16x8*>(xs + sg_lds[s]) = vr[s];
    __syncthreads();

    for (int kc = 0; kc < 8; ++kc) {
        const int cur = kc & 1;

        // issue next chunk's global loads (latency hides under 9-tap compute)
        if (kc < 7) {
            const int ioff = (kc + 1) * 32;
#pragma unroll
            for (int s = 0; s < 4; ++s) {
                bf16x8 v = {0, 0, 0, 0, 0, 0, 0, 0};
                if (sg_ok[s]) v = *reinterpret_cast<const bf16x8*>(sg_ptr[s] + ioff);
                vr[s] = v;
            }
        }

        const char* bufc = xs + cur * XBUF + bLane;
        const int ib = kc * 4 + lhi;
        const ushort* aBase = Ak + (((size_t)b * 9 * 32 + ib) * DD + obase) * 8;

        LDA(0, 0, aBase);
        LDA(1, 1, aBase);
        LDB(0, 0, bufc);
#pragma unroll
        for (int tap = 0; tap < 9; ++tap) {
            const int as = tap % 3;
            if (tap + 2 <= 8) LDA(tap + 2, (tap + 2) % 3, aBase);
            if (tap < 8) LDB(tap + 1, (tap + 1) & 1, bufc);
            const int bs = tap & 1;
            __builtin_amdgcn_s_setprio(1);
#pragma unroll
            for (int fm = 0; fm < 4; ++fm)
#pragma unroll
                for (int fn = 0; fn < 4; ++fn)
                    acc[fm][fn] = __builtin_amdgcn_mfma_f32_16x16x32_bf16(
                        aF[as][fm], bF[bs][fn], acc[fm][fn], 0, 0, 0);
            __builtin_amdgcn_s_setprio(0);
        }

        // write staged chunk to the other buffer (nobody reads it this iter)
        if (kc < 7) {
            char* dstb = xs + (cur ^ 1) * XBUF;
#pragma unroll
            for (int s = 0; s < 4; ++s)
                if (sg_act[s]) *reinterpret_cast<bf16x8*>(dstb + sg_lds[s]) = vr[s];
        }
        __syncthreads();
    }
#undef LDA
#undef LDB

    // epilogue: C/D layout col=lane&15 (px), row=(lane>>4)*4+reg (o)
    const int r_out = r0 + wn;
#pragma unroll
    for (int fm = 0; fm < 4; ++fm) {
#pragma unroll
        for (int fn = 0; fn < 4; ++fn) {
            const int oo = o0 + wm * 64 + fm * 16 + lhi * 4;
            const int cc = fn * 16 + lo;
            float* op = out + (((size_t)(b * DD + oo) * HH) + r_out) * WW + cc;
#pragma unroll
            for (int j = 0; j < 4; ++j) op[(size_t)j * HH * WW] = acc[fm][fn][j];
        }
    }
}

extern "C" void kernel_launch(void* const* d_in, const int* in_sizes, int n_in,
                              void* d_out, int out_size, void* d_ws, size_t ws_size,
                              hipStream_t stream) {
    const float* x            = (const float*)d_in[0];  // (8,256,64,64)
    const float* bank_request = (const float*)d_in[1];  // (8,16)
    const float* style        = (const float*)d_in[2];  // (8,1,256,1,1)
    const float* bank_weight  = (const float*)d_in[3];  // (16,256,256,3,3)
    float* out = (float*)d_out;                         // (8,256,64,64)

    ushort* Ak = (ushort*)d_ws;                         // 8*9*32*256*8 elems
    ushort* xb = Ak + (size_t)8 * 9 * 32 * 256 * 8;     // 8*64*64*256 elems

    cast_x<<<dim3(HH, BB), 256, 0, stream>>>(x, xb);
    prep_filter<<<dim3(DD), 256, 0, stream>>>(bank_request, style, bank_weight, Ak);
    conv_mfma<<<dim3(16, 2, BB), 512, 0, stream>>>(xb, Ak, out);
}